// Round 10
// baseline (299.973 us; speedup 1.0000x reference)
//
#include <hip/hip_runtime.h>
#include <hip/hip_bf16.h>

#define NCH      256
#define NNB      262144
#define BN       128            // double-tile columns
#define NDT      (NNB / BN)     // 2048 dtiles
#define NB       256            // K1 grid: 1 block per CU
#define DTPB     (NDT / NB)     // 8 dtiles per block
#define NENT     (NCH * 6)
#define NTHREADS 512

typedef __bf16        bf16x8 __attribute__((ext_vector_type(8)));
typedef float         f32x4  __attribute__((ext_vector_type(4)));
typedef unsigned int  u32x4  __attribute__((ext_vector_type(4)));
typedef unsigned int  u32x2  __attribute__((ext_vector_type(2)));
typedef short         v4s    __attribute__((ext_vector_type(4)));

union FragU  { u32x4 u; bf16x8 b; };
union Frag2U { u32x2 u; v4s    s; };

__device__ __forceinline__ unsigned pk2(float lo, float hi) {
    union { __hip_bfloat162 h2; unsigned u; } cv;
    cv.h2 = __float22bfloat162_rn(make_float2(lo, hi));
    return cv.u;
}

__device__ __forceinline__ const float* uni_ptr(const float* p) {
    unsigned long long u = (unsigned long long)p;
    unsigned lo = __builtin_amdgcn_readfirstlane((unsigned)u);
    unsigned hi = __builtin_amdgcn_readfirstlane((unsigned)(u >> 32));
    return (const float*)(((unsigned long long)hi << 32) | lo);
}

// raw barrier: LDS writes visible, global loads stay in flight (no vmcnt drain)
#define LBAR() do {                                                  \
    asm volatile("s_waitcnt lgkmcnt(0)" ::: "memory");               \
    __builtin_amdgcn_sched_barrier(0);                               \
    __builtin_amdgcn_s_barrier();                                    \
    __builtin_amdgcn_sched_barrier(0);                               \
} while (0)

// one 16-col compute block: GEMM1 (2 MFMAs per ds_read_b128) + radial + GEMM2
#define CBODY(CB, P)                                                               \
{                                                                                  \
    const int colb = (CB) * 16;                                                    \
    Frag2U gf;                                                                     \
    gf.u = *(const u32x2*)((const char*)gT[P] +                                    \
           (((unsigned)(il * 256 + (colb + q * 4) * 2)) ^                          \
            (((unsigned)(il & 7)) << 3)));                                         \
    f32x4 hp0 = {0.f, 0.f, 0.f, 0.f}, hp1 = {0.f, 0.f, 0.f, 0.f};                  \
    const unsigned rb = (unsigned)((colb + il) * 512);                             \
    const unsigned sw = ((unsigned)(il & 7)) << 4;                                 \
    _Pragma("unroll")                                                              \
    for (int jb = 0; jb < 8; ++jb) {                                               \
        FragU f0;                                                                  \
        f0.u = *(const u32x4*)((const char*)htile[P] +                             \
               ((rb + (unsigned)(jb * 64 + q * 16)) ^ sw));                        \
        hp0 = __builtin_amdgcn_mfma_f32_16x16x32_bf16(f0.b, wf[0][jb].b, hp0, 0, 0, 0); \
        hp1 = __builtin_amdgcn_mfma_f32_16x16x32_bf16(f0.b, wf[1][jb].b, hp1, 0, 0, 0); \
    }                                                                              \
    f32x4 d4 = *(const f32x4*)&dtab[P][0][colb + q * 4];                           \
    f32x4 i4 = *(const f32x4*)&dtab[P][1][colb + q * 4];                           \
    Frag2U a0, a1;                                                                 \
    {                                                                              \
        float m0 = __sinf(fk0 * d4[0]) * i4[0] * hp0[0];                           \
        float m1 = __sinf(fk0 * d4[1]) * i4[1] * hp0[1];                           \
        float m2 = __sinf(fk0 * d4[2]) * i4[2] * hp0[2];                           \
        float m3 = __sinf(fk0 * d4[3]) * i4[3] * hp0[3];                           \
        a0.u[0] = pk2(m0, m1); a0.u[1] = pk2(m2, m3);                              \
        float n0 = __sinf(fk1 * d4[0]) * i4[0] * hp1[0];                           \
        float n1 = __sinf(fk1 * d4[1]) * i4[1] * hp1[1];                           \
        float n2 = __sinf(fk1 * d4[2]) * i4[2] * hp1[2];                           \
        float n3 = __sinf(fk1 * d4[3]) * i4[3] * hp1[3];                           \
        a1.u[0] = pk2(n0, n1); a1.u[1] = pk2(n2, n3);                              \
    }                                                                              \
    acc0 = __builtin_amdgcn_mfma_f32_16x16x16bf16_1k(a0.s, gf.s, acc0, 0, 0, 0);   \
    acc1 = __builtin_amdgcn_mfma_f32_16x16x16bf16_1k(a1.s, gf.s, acc1, 0, 0, 0);   \
}

// issue chunk Q (16 rows x lane's col) of dtile with col-base BASE into DST regs
#define CHUNK_ISSUE(DST, Q, BASE)                                                  \
    _Pragma("unroll")                                                              \
    for (int j = 0; j < 16; ++j)                                                   \
        DST[j] = hwb[(size_t)((Q) * 16 + j) * NNB + (BASE) + sc];

// pack chunk Q into htile[P^1]: rows (wave>>1)*64 + Q*16 .. +16, col sc
#define CHUNK_PACK(SRC, Q, P)                                                      \
{                                                                                  \
    u32x4 w0, w1;                                                                  \
    w0[0] = pk2(SRC[0],  SRC[1]);  w0[1] = pk2(SRC[2],  SRC[3]);                   \
    w0[2] = pk2(SRC[4],  SRC[5]);  w0[3] = pk2(SRC[6],  SRC[7]);                   \
    w1[0] = pk2(SRC[8],  SRC[9]);  w1[1] = pk2(SRC[10], SRC[11]);                  \
    w1[2] = pk2(SRC[12], SRC[13]); w1[3] = pk2(SRC[14], SRC[15]);                  \
    const unsigned boff = (unsigned)(sc * 512 + (wave >> 1) * 128 + (Q) * 32);     \
    *(u32x4*)((char*)htile[(P) ^ 1] + ((boff)      ^ swp)) = w0;                   \
    *(u32x4*)((char*)htile[(P) ^ 1] + ((boff + 16) ^ swp)) = w1;                   \
}

// One iteration: compute dtile (buf P); stage dtile+NB into buf P^1 in 4 chunks,
// each chunk covered by 2 CBODYs (~1000 cyc >= HBM latency), peak 16 fp32 in flight.
#define ITER(P, CUR, NXT, DT_EXPR)                                                 \
{                                                                                  \
    const int dt  = (DT_EXPR);                                                     \
    const int dn1 = dt + NB;                                                       \
    const int dn2 = dt + 2 * NB;                                                   \
    const unsigned base1 = (unsigned)(((dn1 < NDT) ? dn1 : dt) * BN);              \
    {   /* issue rp(dn2) -> NXT */                                                 \
        const int lt = (dn2 < NDT) ? dn2 : dt;                                     \
        const unsigned ii = (unsigned)(lt * BN) + (unsigned)(t & 127);             \
        NXT[0] = rp[ii];                                                           \
        NXT[1] = rp[(size_t)NNB + ii];                                             \
        NXT[2] = rp[2 * (size_t)NNB + ii];                                         \
    }                                                                              \
    float hA[16], hB[16], hC[16], hD[16];                                          \
    if (dn1 < NDT) { CHUNK_ISSUE(hA, 0, base1) }                                   \
    __builtin_amdgcn_sched_barrier(0);                                             \
    CBODY(0, P) CBODY(1, P)                                                        \
    __builtin_amdgcn_sched_barrier(0);                                             \
    if (dn1 < NDT) { CHUNK_PACK(hA, 0, P) CHUNK_ISSUE(hB, 1, base1) }              \
    __builtin_amdgcn_sched_barrier(0);                                             \
    CBODY(2, P) CBODY(3, P)                                                        \
    __builtin_amdgcn_sched_barrier(0);                                             \
    if (dn1 < NDT) { CHUNK_PACK(hB, 1, P) CHUNK_ISSUE(hC, 2, base1) }              \
    __builtin_amdgcn_sched_barrier(0);                                             \
    CBODY(4, P) CBODY(5, P)                                                        \
    __builtin_amdgcn_sched_barrier(0);                                             \
    if (dn1 < NDT) { CHUNK_PACK(hC, 2, P) CHUNK_ISSUE(hD, 3, base1) }              \
    __builtin_amdgcn_sched_barrier(0);                                             \
    CBODY(6, P) CBODY(7, P)                                                        \
    __builtin_amdgcn_sched_barrier(0);                                             \
    if (dn1 < NDT) {                                                               \
        CHUNK_PACK(hD, 3, P)                                                       \
        if (t < 128) {   /* geometry for dtile dn1 from CUR */                     \
            const int cc = t;                                                      \
            float dd = sqrtf(CUR[0] * CUR[0] + CUR[1] * CUR[1] + CUR[2] * CUR[2]); \
            float iv = 1.0f / dd;                                                  \
            dtab[(P) ^ 1][0][cc] = dd;                                             \
            dtab[(P) ^ 1][1][cc] = iv;                                             \
            float i2 = iv * iv;                                                    \
            float gg[6] = { CUR[0] * CUR[0] * i2, CUR[0] * CUR[1] * i2,            \
                            CUR[0] * CUR[2] * i2, CUR[1] * CUR[1] * i2,            \
                            CUR[1] * CUR[2] * i2, CUR[2] * CUR[2] * i2 };          \
            _Pragma("unroll")                                                      \
            for (int de = 0; de < 6; ++de) {                                       \
                unsigned off = ((unsigned)(de * 256 + cc * 2)) ^                   \
                               (((unsigned)de) << 3);                              \
                *(unsigned short*)((char*)gT[(P) ^ 1] + off) =                     \
                    (unsigned short)(pk2(gg[de], 0.f) & 0xffffu);                  \
            }                                                                      \
        }                                                                          \
    }                                                                              \
    LBAR();                                                                        \
}

// K1: 512 threads = 8 waves, 1 block/CU (LDS 138 KB).
// Staging: wave-pair p = wave>>1 stages rows [p*64,+64); the pair's two waves
// cover adjacent 64-col halves -> concurrent adjacent 256B segments per row
// (512B effective DRAM bursts). Compute: wave owns k [wave*32,+32) over all
// 128 cols; each ds_read_b128 feeds 2 MFMAs.
// ws layout: [block][entry = k*6 + m6]
__global__ __launch_bounds__(NTHREADS, 2) void create_As_k1(
        const float* __restrict__ h, const float* __restrict__ rp,
        const float* __restrict__ W, float* __restrict__ ws)
{
    __shared__ unsigned short htile[2][BN * NCH];        // 2 x 64 KB [col][j], ^((col&7)<<4)
    __shared__ unsigned short gT[2][16 * BN];            // 2 x 4 KB [de][col], ^((de&7)<<3)
    __shared__ __align__(16) float dtab[2][2][BN];       // [p][{d,invd}][col]

    const int t    = threadIdx.x;
    const int wave = t >> 6;        // 0..7
    const int l    = t & 63;
    const int il   = t & 15;
    const int q    = (t >> 4) & 3;
    const int k0   = wave * 32;
    const int sc   = (wave & 1) * 64 + l;          // staging column within dtile
    const unsigned swp = ((unsigned)(l & 7)) << 4; // (sc&7)<<4 == (l&7)<<4
    const float fk0 = (float)(k0 + il + 1);
    const float fk1 = fk0 + 16.0f;

    // zero gT (rows 6..15 must stay zero): 4096 u32, 512 threads x 8
    #pragma unroll
    for (int z = 0; z < 8; ++z) ((unsigned*)gT)[t + z * NTHREADS] = 0u;

    // W fragments: lane holds W[k0 + kt*16 + il][jb*32 + q*8 + e]  (64 VGPR)
    FragU wf[2][8];
    #pragma unroll
    for (int kt = 0; kt < 2; ++kt) {
        const float* wr = W + (size_t)(k0 + kt * 16 + il) * NCH + q * 8;
        #pragma unroll
        for (int jb = 0; jb < 8; ++jb) {
            f32x4 a = *(const f32x4*)(wr + jb * 32);
            f32x4 b = *(const f32x4*)(wr + jb * 32 + 4);
            wf[kt][jb].u[0] = pk2(a[0], a[1]);
            wf[kt][jb].u[1] = pk2(a[2], a[3]);
            wf[kt][jb].u[2] = pk2(b[0], b[1]);
            wf[kt][jb].u[3] = pk2(b[2], b[3]);
        }
    }

    f32x4 acc0 = {0.f, 0.f, 0.f, 0.f};
    f32x4 acc1 = {0.f, 0.f, 0.f, 0.f};

    // staging row base: wave-pair p stages rows [p*64, +64)
    const float* hwb = uni_ptr(h + (size_t)((wave >> 1) * 64) * NNB);

    float pA[3], pB[3];
    const int d0 = blockIdx.x;

    __syncthreads();   // gT zero-init visible before prologue writes

    // -------- prologue: stage dtile d0 into buf 0 (4 sequential chunks) --------
    {
        const unsigned ii = (unsigned)(d0 * BN) + (unsigned)(t & 127);
        pB[0] = rp[ii]; pB[1] = rp[(size_t)NNB + ii]; pB[2] = rp[2 * (size_t)NNB + ii];
        const unsigned base = (unsigned)(d0 * BN);
        #pragma unroll
        for (int qq = 0; qq < 4; ++qq) {
            float hv[16];
            #pragma unroll
            for (int j = 0; j < 16; ++j)
                hv[j] = hwb[(size_t)(qq * 16 + j) * NNB + base + sc];
            u32x4 w0, w1;
            w0[0] = pk2(hv[0],  hv[1]);  w0[1] = pk2(hv[2],  hv[3]);
            w0[2] = pk2(hv[4],  hv[5]);  w0[3] = pk2(hv[6],  hv[7]);
            w1[0] = pk2(hv[8],  hv[9]);  w1[1] = pk2(hv[10], hv[11]);
            w1[2] = pk2(hv[12], hv[13]); w1[3] = pk2(hv[14], hv[15]);
            const unsigned boff = (unsigned)(sc * 512 + (wave >> 1) * 128 + qq * 32);
            *(u32x4*)((char*)htile[0] + ((boff)      ^ swp)) = w0;
            *(u32x4*)((char*)htile[0] + ((boff + 16) ^ swp)) = w1;
        }
        if (t < 128) {
            const int cc = t;
            float dd = sqrtf(pB[0] * pB[0] + pB[1] * pB[1] + pB[2] * pB[2]);
            float iv = 1.0f / dd;
            dtab[0][0][cc] = dd; dtab[0][1][cc] = iv;
            float i2 = iv * iv;
            float gg[6] = { pB[0] * pB[0] * i2, pB[0] * pB[1] * i2, pB[0] * pB[2] * i2,
                            pB[1] * pB[1] * i2, pB[1] * pB[2] * i2, pB[2] * pB[2] * i2 };
            #pragma unroll
            for (int de = 0; de < 6; ++de) {
                unsigned off = ((unsigned)(de * 256 + cc * 2)) ^ (((unsigned)de) << 3);
                *(unsigned short*)((char*)gT[0] + off) =
                    (unsigned short)(pk2(gg[de], 0.f) & 0xffffu);
            }
        }
        // issue rp(d0+NB) -> pA
        const unsigned i1 = (unsigned)((d0 + NB) * BN) + (unsigned)(t & 127);
        pA[0] = rp[i1]; pA[1] = rp[(size_t)NNB + i1]; pA[2] = rp[2 * (size_t)NNB + i1];
    }
    LBAR();

    #pragma unroll 1
    for (int it2 = 0; it2 < DTPB; it2 += 2) {
        const int db = d0 + it2 * NB;
        ITER(0, pA, pB, db)
        ITER(1, pB, pA, db + NB)
    }

    // ---- store: lane holds A[k = k0 + q*4 + r (+16)][de = il] ----
    if (il < 6) {
        float* dst = ws + (size_t)blockIdx.x * NENT;
        #pragma unroll
        for (int r = 0; r < 4; ++r) {
            dst[(k0 + q * 4 + r) * 6 + il]      = acc0[r];
            dst[(k0 + 16 + q * 4 + r) * 6 + il] = acc1[r];
        }
    }
}

// K2: 24 blocks x 512. Block eb owns entries [eb*64, +64); coalesced rows; LDS reduce.
__global__ void create_As_k2(const float* __restrict__ ws, float* __restrict__ out)
{
    __shared__ float red[8][64];
    const int eb = blockIdx.x;
    const int w  = threadIdx.x >> 6;
    const int l  = threadIdx.x & 63;
    float s = 0.f;
    #pragma unroll 4
    for (int b = w; b < NB; b += 8)
        s += ws[(size_t)b * NENT + (unsigned)(eb * 64 + l)];
    red[w][l] = s;
    __syncthreads();
    if (w == 0) {
        float v = red[0][l] + red[1][l] + red[2][l] + red[3][l]
                + red[4][l] + red[5][l] + red[6][l] + red[7][l];
        const int e  = eb * 64 + l;
        const int k  = e / 6;
        const int m6 = e - k * 6;
        const int d  = (m6 < 3) ? 0 : ((m6 < 5) ? 1 : 2);
        const int e2 = (m6 < 3) ? m6 : ((m6 < 5) ? (m6 - 2) : 2);
        out[k * 9 + d * 3 + e2] = v;
        if (d != e2) out[k * 9 + e2 * 3 + d] = v;
    }
}

extern "C" void kernel_launch(void* const* d_in, const int* in_sizes, int n_in,
                              void* d_out, int out_size, void* d_ws, size_t ws_size,
                              hipStream_t stream)
{
    const float* h  = (const float*)d_in[0];
    const float* rp = (const float*)d_in[1];
    const float* W  = (const float*)d_in[2];
    float* out = (float*)d_out;
    float* ws  = (float*)d_ws;

    hipLaunchKernelGGL(create_As_k1, dim3(NB), dim3(NTHREADS), 0, stream, h, rp, W, ws);
    hipLaunchKernelGGL(create_As_k2, dim3(NENT / 64), dim3(512), 0, stream, ws, out);
}

// Round 11
// 83.423 us; speedup vs baseline: 3.5958x; 3.5958x over previous
//
#include <hip/hip_runtime.h>
#include <hip/hip_bf16.h>

#define NCH      256
#define NNB      262144
#define BN       64
#define NTILES   (NNB / BN)   // 4096
#define NB       512          // K1 grid: 2 blocks per CU
#define ITPB     (NTILES / NB) // 8 tiles per block
#define NENT     (NCH * 6)
#define NTHREADS 512

typedef __bf16        bf16x8 __attribute__((ext_vector_type(8)));
typedef float         f32x4  __attribute__((ext_vector_type(4)));
typedef unsigned int  u32x4  __attribute__((ext_vector_type(4)));
typedef unsigned int  u32x2  __attribute__((ext_vector_type(2)));
typedef short         v4s    __attribute__((ext_vector_type(4)));

union FragU  { u32x4 u; bf16x8 b; };
union Frag2U { u32x2 u; v4s    s; };

__device__ __forceinline__ unsigned pk2(float lo, float hi) {
    union { __hip_bfloat162 h2; unsigned u; } cv;
    cv.h2 = __float22bfloat162_rn(make_float2(lo, hi));
    return cv.u;
}

__device__ __forceinline__ const float* uni_ptr(const float* p) {
    unsigned long long u = (unsigned long long)p;
    unsigned lo = __builtin_amdgcn_readfirstlane((unsigned)u);
    unsigned hi = __builtin_amdgcn_readfirstlane((unsigned)(u >> 32));
    return (const float*)(((unsigned long long)hi << 32) | lo);
}

// raw barrier: LDS writes visible, global loads stay in flight (no vmcnt drain)
#define LBAR() do {                                                  \
    asm volatile("s_waitcnt lgkmcnt(0)" ::: "memory");               \
    __builtin_amdgcn_sched_barrier(0);                               \
    __builtin_amdgcn_s_barrier();                                    \
    __builtin_amdgcn_sched_barrier(0);                               \
} while (0)

// one 16-col compute block: GEMM1 (2 MFMAs per ds_read_b128) + radial + GEMM2
// htP: current bf16 h-tile; gTP: current G table; dtP: current {d[64], invd[64]}
#define CBODY(CB)                                                                  \
{                                                                                  \
    const int colb = (CB) * 16;                                                    \
    Frag2U gf;                                                                     \
    gf.u = *(const u32x2*)(gTP +                                                   \
           (((unsigned)(il * 128 + (colb + q * 4) * 2)) ^                          \
            (((unsigned)(il & 7)) << 3)));                                         \
    f32x4 hp0 = {0.f, 0.f, 0.f, 0.f}, hp1 = {0.f, 0.f, 0.f, 0.f};                  \
    const unsigned rb = (unsigned)((colb + il) * 512);                             \
    _Pragma("unroll")                                                              \
    for (int jb = 0; jb < 8; ++jb) {                                               \
        FragU f0;                                                                  \
        f0.u = *(const u32x4*)((const char*)htP +                                  \
               ((rb + (unsigned)(jb * 64 + q * 16)) ^ sw));                        \
        hp0 = __builtin_amdgcn_mfma_f32_16x16x32_bf16(f0.b, wf[0][jb].b, hp0, 0, 0, 0); \
        hp1 = __builtin_amdgcn_mfma_f32_16x16x32_bf16(f0.b, wf[1][jb].b, hp1, 0, 0, 0); \
    }                                                                              \
    f32x4 d4 = *(const f32x4*)(dtP + colb + q * 4);                                \
    f32x4 i4 = *(const f32x4*)(dtP + 64 + colb + q * 4);                           \
    Frag2U a0, a1;                                                                 \
    {                                                                              \
        float m0 = __sinf(fk0 * d4[0]) * i4[0] * hp0[0];                           \
        float m1 = __sinf(fk0 * d4[1]) * i4[1] * hp0[1];                           \
        float m2 = __sinf(fk0 * d4[2]) * i4[2] * hp0[2];                           \
        float m3 = __sinf(fk0 * d4[3]) * i4[3] * hp0[3];                           \
        a0.u[0] = pk2(m0, m1); a0.u[1] = pk2(m2, m3);                              \
        float n0 = __sinf(fk1 * d4[0]) * i4[0] * hp1[0];                           \
        float n1 = __sinf(fk1 * d4[1]) * i4[1] * hp1[1];                           \
        float n2 = __sinf(fk1 * d4[2]) * i4[2] * hp1[2];                           \
        float n3 = __sinf(fk1 * d4[3]) * i4[3] * hp1[3];                           \
        a1.u[0] = pk2(n0, n1); a1.u[1] = pk2(n2, n3);                              \
    }                                                                              \
    acc0 = __builtin_amdgcn_mfma_f32_16x16x16bf16_1k(a0.s, gf.s, acc0, 0, 0, 0);   \
    acc1 = __builtin_amdgcn_mfma_f32_16x16x16bf16_1k(a1.s, gf.s, acc1, 0, 0, 0);   \
}

// issue 8-row chunk Q of next tile (col c) into hc[8]
#define CHUNK8_ISSUE(Q)                                                            \
    if (hasNext) {                                                                 \
        _Pragma("unroll")                                                          \
        for (int j = 0; j < 8; ++j)                                                \
            hc[j] = hwb[(size_t)((Q) * 8 + j) * NNB + baseN + c];                  \
    }

// pack chunk Q (8 rows) into htN: one b128 at col c, rows wave*32 + Q*8 .. +8
#define CHUNK8_PACK(Q)                                                             \
    if (hasNext) {                                                                 \
        u32x4 w0;                                                                  \
        w0[0] = pk2(hc[0], hc[1]); w0[1] = pk2(hc[2], hc[3]);                      \
        w0[2] = pk2(hc[4], hc[5]); w0[3] = pk2(hc[6], hc[7]);                      \
        *(u32x4*)((char*)htN +                                                     \
            (((unsigned)(c * 512 + wave * 64 + (Q) * 16)) ^ swc)) = w0;            \
    }

// K1: 512 threads = 8 waves, 2 blocks/CU. Wave owns k [wave*32,+32) over all
// 64 cols; each ds_read_b128 feeds 2 MFMAs (halved LDS amplification).
// Register diet vs R8/R10 (which spilled ~20 regs): staging in 4 chunks of 8
// (one per CBODY; peak 16 staging regs, was 32) and rp/geometry on wave 0 only
// (no all-thread pA/pB ping-pong). Peak live ~125 <= 128 budget at (512,2).
// ws layout: [block][entry = k*6 + m6]
__global__ __launch_bounds__(NTHREADS, 2) void create_As_k1(
        const float* __restrict__ h, const float* __restrict__ rp,
        const float* __restrict__ W, float* __restrict__ ws)
{
    __shared__ unsigned short htile[2][BN * NCH];        // 2 x 32 KB [col][j], ^((col&7)<<4)
    __shared__ unsigned short gT[2][16 * BN];            // 2 x 2 KB [de][col], ^((de&7)<<3)
    __shared__ __align__(16) float dtab[2][2][BN];       // [p][{d,invd}][col]

    const int t    = threadIdx.x;
    const int wave = t >> 6;        // 0..7
    const int il   = t & 15;
    const int q    = (t >> 4) & 3;
    const int c    = t & 63;
    const int k0   = wave * 32;
    const unsigned sw  = ((unsigned)(il & 7)) << 4;
    const unsigned swc = ((unsigned)(c & 7)) << 4;
    const float fk0 = (float)(k0 + il + 1);
    const float fk1 = fk0 + 16.0f;

    // zero gT (rows 6..15 must stay zero): 1024 u32, 512 threads x 2
    #pragma unroll
    for (int z = 0; z < 2; ++z) ((unsigned*)gT)[t + z * NTHREADS] = 0u;

    // W fragments: lane holds W[k0 + kt*16 + il][jb*32 + q*8 + e]  (64 VGPR resident)
    FragU wf[2][8];
    #pragma unroll
    for (int kt = 0; kt < 2; ++kt) {
        const float* wr = W + (size_t)(k0 + kt * 16 + il) * NCH + q * 8;
        #pragma unroll
        for (int jb = 0; jb < 8; ++jb) {
            f32x4 a = *(const f32x4*)(wr + jb * 32);
            f32x4 b = *(const f32x4*)(wr + jb * 32 + 4);
            wf[kt][jb].u[0] = pk2(a[0], a[1]);
            wf[kt][jb].u[1] = pk2(a[2], a[3]);
            wf[kt][jb].u[2] = pk2(b[0], b[1]);
            wf[kt][jb].u[3] = pk2(b[2], b[3]);
        }
    }

    f32x4 acc0 = {0.f, 0.f, 0.f, 0.f};
    f32x4 acc1 = {0.f, 0.f, 0.f, 0.f};

    // staging rows: wave stages rows [wave*32, +32) at its lane's col c
    const float* hwb = uni_ptr(h + (size_t)(wave * 32) * NNB);

    const int d0 = blockIdx.x;

    __syncthreads();   // gT zero-init visible before prologue writes

    // -------- prologue: stage tile d0 into buf 0; geometry d0 (wave 0) --------
    {
        const unsigned base = (unsigned)(d0 * BN);
        #pragma unroll
        for (int qq = 0; qq < 4; ++qq) {
            float hv[8];
            #pragma unroll
            for (int j = 0; j < 8; ++j)
                hv[j] = hwb[(size_t)(qq * 8 + j) * NNB + base + c];
            u32x4 w0;
            w0[0] = pk2(hv[0], hv[1]); w0[1] = pk2(hv[2], hv[3]);
            w0[2] = pk2(hv[4], hv[5]); w0[3] = pk2(hv[6], hv[7]);
            *(u32x4*)((char*)htile[0] +
                (((unsigned)(c * 512 + wave * 64 + qq * 16)) ^ swc)) = w0;
        }
        if (t < 64) {
            const unsigned ii = base + (unsigned)c;
            float gx = rp[ii], gy = rp[(size_t)NNB + ii], gz = rp[2 * (size_t)NNB + ii];
            float dd = sqrtf(gx * gx + gy * gy + gz * gz);
            float iv = 1.0f / dd;
            dtab[0][0][c] = dd; dtab[0][1][c] = iv;
            float i2 = iv * iv;
            float gg[6] = { gx * gx * i2, gx * gy * i2, gx * gz * i2,
                            gy * gy * i2, gy * gz * i2, gz * gz * i2 };
            #pragma unroll
            for (int de = 0; de < 6; ++de) {
                unsigned off = ((unsigned)(de * 128 + c * 2)) ^ (((unsigned)de) << 3);
                *(unsigned short*)((char*)gT[0] + off) =
                    (unsigned short)(pk2(gg[de], 0.f) & 0xffffu);
            }
        }
    }
    LBAR();

    #pragma unroll 1
    for (int it = 0; it < ITPB; ++it) {
        const int P = it & 1;
        const unsigned short* htP = htile[P];
        unsigned short*       htN = htile[P ^ 1];
        const char*  gTP = (const char*)gT[P];
        const float* dtP = &dtab[P][0][0];
        const bool hasNext = (it + 1 < ITPB);
        const unsigned baseN = (unsigned)((d0 + (it + 1) * NB) * BN);

        // geometry rp for next tile: wave 0 only, issued early, consumed at end
        float gx = 0.f, gy = 0.f, gz = 0.f;
        if (hasNext && t < 64) {
            const unsigned ii = baseN + (unsigned)c;
            gx = rp[ii]; gy = rp[(size_t)NNB + ii]; gz = rp[2 * (size_t)NNB + ii];
        }

        float hc[8];
        CHUNK8_ISSUE(0)
        __builtin_amdgcn_sched_barrier(0);
        CBODY(0)
        __builtin_amdgcn_sched_barrier(0);
        CHUNK8_PACK(0) CHUNK8_ISSUE(1)
        __builtin_amdgcn_sched_barrier(0);
        CBODY(1)
        __builtin_amdgcn_sched_barrier(0);
        CHUNK8_PACK(1) CHUNK8_ISSUE(2)
        __builtin_amdgcn_sched_barrier(0);
        CBODY(2)
        __builtin_amdgcn_sched_barrier(0);
        CHUNK8_PACK(2) CHUNK8_ISSUE(3)
        __builtin_amdgcn_sched_barrier(0);
        CBODY(3)
        __builtin_amdgcn_sched_barrier(0);
        CHUNK8_PACK(3)
        if (hasNext && t < 64) {   // geometry for next tile into buf P^1
            float dd = sqrtf(gx * gx + gy * gy + gz * gz);
            float iv = 1.0f / dd;
            dtab[P ^ 1][0][c] = dd; dtab[P ^ 1][1][c] = iv;
            float i2 = iv * iv;
            float gg[6] = { gx * gx * i2, gx * gy * i2, gx * gz * i2,
                            gy * gy * i2, gy * gz * i2, gz * gz * i2 };
            #pragma unroll
            for (int de = 0; de < 6; ++de) {
                unsigned off = ((unsigned)(de * 128 + c * 2)) ^ (((unsigned)de) << 3);
                *(unsigned short*)((char*)gT[P ^ 1] + off) =
                    (unsigned short)(pk2(gg[de], 0.f) & 0xffffu);
            }
        }
        LBAR();
    }

    // ---- store: lane holds A[k = k0 + q*4 + r (+16)][de = il] ----
    if (il < 6) {
        float* dst = ws + (size_t)blockIdx.x * NENT;
        #pragma unroll
        for (int r = 0; r < 4; ++r) {
            dst[(k0 + q * 4 + r) * 6 + il]      = acc0[r];
            dst[(k0 + 16 + q * 4 + r) * 6 + il] = acc1[r];
        }
    }
}

// K2: 24 blocks x 512. Block eb owns entries [eb*64, +64); coalesced rows; LDS reduce.
__global__ void create_As_k2(const float* __restrict__ ws, float* __restrict__ out)
{
    __shared__ float red[8][64];
    const int eb = blockIdx.x;
    const int w  = threadIdx.x >> 6;
    const int l  = threadIdx.x & 63;
    float s = 0.f;
    #pragma unroll 4
    for (int b = w; b < NB; b += 8)
        s += ws[(size_t)b * NENT + (unsigned)(eb * 64 + l)];
    red[w][l] = s;
    __syncthreads();
    if (w == 0) {
        float v = red[0][l] + red[1][l] + red[2][l] + red[3][l]
                + red[4][l] + red[5][l] + red[6][l] + red[7][l];
        const int e  = eb * 64 + l;
        const int k  = e / 6;
        const int m6 = e - k * 6;
        const int d  = (m6 < 3) ? 0 : ((m6 < 5) ? 1 : 2);
        const int e2 = (m6 < 3) ? m6 : ((m6 < 5) ? (m6 - 2) : 2);
        out[k * 9 + d * 3 + e2] = v;
        if (d != e2) out[k * 9 + e2 * 3 + d] = v;
    }
}

extern "C" void kernel_launch(void* const* d_in, const int* in_sizes, int n_in,
                              void* d_out, int out_size, void* d_ws, size_t ws_size,
                              hipStream_t stream)
{
    const float* h  = (const float*)d_in[0];
    const float* rp = (const float*)d_in[1];
    const float* W  = (const float*)d_in[2];
    float* out = (float*)d_out;
    float* ws  = (float*)d_ws;

    hipLaunchKernelGGL(create_As_k1, dim3(NB), dim3(NTHREADS), 0, stream, h, rp, W, ws);
    hipLaunchKernelGGL(create_As_k2, dim3(NENT / 64), dim3(512), 0, stream, ws, out);
}